// Round 14
// baseline (108.286 us; speedup 1.0000x reference)
//
#include <hip/hip_runtime.h>

typedef float f32x4 __attribute__((ext_vector_type(4)));

#define NBINS 1024   // labels < 1000
#define SLOT  64     // max bucket entries used (avg 16.4, max ~40; fallback otherwise)
#define APB   16     // anchors per block (4 waves x 4 anchors)
#define BLOCK 256

// Node 1: zero cnt[NBINS] and the barrier cell cnt[NBINS]. Tiny (4.1 KB).
__global__ void zero_kernel(int* __restrict__ cnt) {
    for (int k = threadIdx.x; k <= NBINS; k += BLOCK) cnt[k] = 0;
}

// Node 2: scatter -> grid barrier (bounded spin, fallback-safe) -> resolve+gather.
//  pos: min-reduce over the anchor's label bucket (1 masked load + 6 shfl),
//       replacing the ~1000-label forward scan (~8 KB L2 reads per wave).
//  neg + anchor row + labels: loaded PRE-barrier (independent of buckets),
//       hidden under the barrier wait.
//  Barrier: bounded spin; on timeout (or bucket overflow) -> ballot-scan
//       fallback, so output is deterministic and deadlock is impossible.
__global__ void __launch_bounds__(BLOCK, 4) mega_kernel(
    const int* __restrict__ labels,
    const f32x4* __restrict__ emb,    // [N][32]
    f32x4* __restrict__ out,          // [3][N][32]
    float* __restrict__ valid_out,    // [N]
    int* __restrict__ cnt,            // [NBINS] counts, [NBINS] = barrier
    int* __restrict__ items,          // [NBINS][SLOT]
    int N) {

    const int D4 = 32;
    const int INF = 0x7FFFFFFF;
    int tid  = threadIdx.x, bid = blockIdx.x;
    int lane = tid & 63, w = tid >> 6, d4 = lane & 31;

    // --- Phase S: scatter this block's APB labels into buckets ---
    if (tid < APB) {
        int i = bid * APB + tid;
        if (i < N) {
            int c = labels[i];
            if ((unsigned)c < NBINS) {
                int r = atomicAdd(&cnt[c], 1);        // device-scope RMW
                if (r < SLOT)
                    __hip_atomic_store(&items[c * SLOT + r], i,
                                       __ATOMIC_RELEASE, __HIP_MEMORY_SCOPE_AGENT);
            }
        }
    }

    // --- Pre-barrier independent work (hidden under barrier wait) ---
    int ibase = bid * APB + w * 4;
    int my[4]; f32x4 ea[4]; int ngr[4];
    #pragma unroll
    for (int a = 0; a < 4; ++a) {
        int i = ibase + a;
        bool live = (i < N);
        my[a]  = live ? labels[i] : 0;
        ea[a]  = live ? emb[(size_t)i * D4 + d4] : f32x4{0, 0, 0, 0};
        ngr[a] = -1;
        if (live) {
            for (int base = i + 1; base < N; base += 64) {   // expected 1 iter
                int j = base + lane;
                unsigned long long bd = __ballot(j < N && labels[j] != my[a]);
                if (bd) { ngr[a] = base + (int)__ffsll(bd) - 1; break; }
            }
        }
    }

    // --- Grid barrier: arrive, bounded spin (no deadlock possible) ---
    __shared__ int okflag;
    __syncthreads();                   // scatter stores of this block done
    if (tid == 0) {
        __hip_atomic_fetch_add(&cnt[NBINS], 1, __ATOMIC_ACQ_REL,
                               __HIP_MEMORY_SCOPE_AGENT);
        int v = 0, it = 0;
        do {
            v = __hip_atomic_load(&cnt[NBINS], __ATOMIC_ACQUIRE,
                                  __HIP_MEMORY_SCOPE_AGENT);
        } while (v < (int)gridDim.x && ++it < (1 << 14));
        okflag = (v >= (int)gridDim.x);
    }
    __syncthreads();
    bool ok = (okflag != 0);

    // --- Phase R: resolve pos + gather + store, 4 anchors per wave ---
    size_t ND4 = (size_t)N * D4;
    #pragma unroll
    for (int a = 0; a < 4; ++a) {
        int i = ibase + a;
        if (i >= N) break;

        int p = -1; bool fast = false;
        if (ok && (unsigned)my[a] < NBINS) {
            int n = __hip_atomic_load(&cnt[my[a]], __ATOMIC_RELAXED,
                                      __HIP_MEMORY_SCOPE_AGENT);
            if (n <= SLOT) {
                fast = true;
                int v0 = (lane < n)
                    ? __hip_atomic_load(&items[my[a] * SLOT + lane],
                                        __ATOMIC_RELAXED, __HIP_MEMORY_SCOPE_AGENT)
                    : INF;
                if (v0 <= i) v0 = INF;                 // need j > i
                #pragma unroll
                for (int off = 32; off; off >>= 1)
                    v0 = min(v0, __shfl_xor(v0, off));
                if (v0 != INF) p = v0;
            }
        }
        if (!fast) {   // overflow / barrier-timeout fallback: same result, slower
            for (int base = i + 1; base < N; base += 64) {
                int j = base + lane;
                unsigned long long bs = __ballot(j < N && labels[j] == my[a]);
                if (bs) { p = base + (int)__ffsll(bs) - 1; break; }
            }
        }

        float v  = (p >= 0 && ngr[a] >= 0) ? 1.0f : 0.0f;
        int   ps = (p      >= 0) ? p      : 0;
        int   ns = (ngr[a] >= 0) ? ngr[a] : 0;

        if (lane == 0) valid_out[i] = v;

        // Combined gather: lanes<32 -> neg row, lanes>=32 -> pos row.
        int gsrc = (lane < 32) ? ns : ps;
        f32x4 eg = emb[(size_t)gsrc * D4 + d4];

        int   t  = lane >> 5;
        f32x4 r0 = (lane < 32) ? ea[a] : eg;
        out[(size_t)t * ND4 + (size_t)i * D4 + d4] = r0 * v;   // anchor | pos
        if (lane < 32)
            out[2 * ND4 + (size_t)i * D4 + d4] = eg * v;       // neg
    }
}

extern "C" void kernel_launch(void* const* d_in, const int* in_sizes, int n_in,
                              void* d_out, int out_size, void* d_ws, size_t ws_size,
                              hipStream_t stream) {
    const float* emb    = (const float*)d_in[0];
    const int*   labels = (const int*)d_in[1];   // harness passes integers as int32

    int N = in_sizes[1];             // 16384
    int D = in_sizes[0] / N;         // 128 (D4 = 32 hard-wired in kernel)

    float* out       = (float*)d_out;
    float* valid_out = out + (size_t)3 * N * D;  // tail of d_out: [N] valid mask

    int* cnt   = (int*)d_ws;                     // [NBINS] + barrier cell
    int* items = cnt + NBINS + 1;                // [NBINS][SLOT]

    zero_kernel<<<1, BLOCK, 0, stream>>>(cnt);

    int nblk = (N + APB - 1) / APB;              // 1024 blocks for N=16384
    mega_kernel<<<nblk, BLOCK, 0, stream>>>(
        labels, (const f32x4*)emb, (f32x4*)out, valid_out, cnt, items, N);
}

// Round 15
// 18.880 us; speedup vs baseline: 5.7356x; 5.7356x over previous
//
#include <hip/hip_runtime.h>

typedef float f32x4 __attribute__((ext_vector_type(4)));

#define BLOCK 256   // 4 waves/block; TWO adjacent anchors per wave

// Fused triplet miner: 2 ADJACENT ANCHORS PER WAVE, one shared label stream.
//  - anchors i0=2*wid, i1=i0+1 scan the SAME chunks (one int4/lane, 256
//    labels/iter, 2-deep prefetch) -> label traffic and generations halved
//    vs wave-per-anchor, with only 4 ballots/iter (vs round-8's 16).
//  - first-iteration j>i masking needed only in lane 0 (per anchor).
//  - match masks captured at ballot time; post-loop resolve = shfl+ffs.
//  - anchor emb rows loaded pre-scan; pos+neg rows one combined gather each.
//  - single dispatch (multi-node graphs cost ~2-4 us/node).
__global__ void __launch_bounds__(BLOCK, 8) triplet_fused_kernel(
    const int* __restrict__ labels,
    const f32x4* __restrict__ emb,    // [N][32]
    f32x4* __restrict__ out,          // [3][N][32]
    float* __restrict__ valid_out,    // [N]
    int N) {

    const int D4 = 32;
    int lane = threadIdx.x & 63;
    int wid  = blockIdx.x * (BLOCK >> 6) + (threadIdx.x >> 6);
    int i0 = wid * 2, i1 = i0 + 1;
    if (i0 >= N) return;
    bool has1 = (i1 < N);

    // Early independent loads (hidden under the scan).
    int d4 = lane & 31;
    f32x4 ea0 = emb[(size_t)i0 * D4 + d4];
    f32x4 ea1 = has1 ? emb[(size_t)i1 * D4 + d4] : f32x4{0, 0, 0, 0};
    int my0 = labels[i0];
    int my1 = has1 ? labels[i1] : my0;

    const int4* lab4 = (const int4*)labels;
    int nq = N >> 2;                  // N % 4 == 0
    int kb = (i0 + 1) >> 2;           // first chunk containing j > i0

    // First-iteration validity masks (lane 0's chunk only can hold j <= i).
    unsigned mv0 = 0xFu, mv1 = 0xFu;
    if (lane == 0) {
        int j0 = kb << 2;
        unsigned m0 = 0, m1 = 0;
        #pragma unroll
        for (int b = 0; b < 4; ++b) {
            int j = j0 + b;
            if (j > i0) m0 |= (1u << b);
            if (j > i1) m1 |= (1u << b);
        }
        mv0 = m0; mv1 = m1;
    }
    // (all chunks >= kb+1 contain only j >= kb*4+4 > i1 -- always valid)

    bool fp0 = false, fn0 = false, fp1 = !has1, fn1 = !has1;
    unsigned long long balP0 = 0, balN0 = 0, balP1 = 0, balN1 = 0;
    int baseP0 = 0, baseN0 = 0, baseP1 = 0, baseN1 = 0;
    unsigned msP0 = 0, msN0 = 0, msP1 = 0, msN1 = 0;

    if (kb < nq) {
        int4 c0 = lab4[min(kb +      lane, nq - 1)];
        int4 c1 = lab4[min(kb + 64 + lane, nq - 1)];
        int kbase = kb;
        while (true) {
            int4 c2 = lab4[min(kbase + 128 + lane, nq - 1)];

            unsigned mvc = ((kbase + lane) < nq) ? 0xFu : 0u;
            unsigned m0v = mv0 & mvc, m1v = mv1 & mvc;

            unsigned e0 = (c0.x == my0 ? 1u : 0u) | (c0.y == my0 ? 2u : 0u)
                        | (c0.z == my0 ? 4u : 0u) | (c0.w == my0 ? 8u : 0u);
            unsigned e1 = (c0.x == my1 ? 1u : 0u) | (c0.y == my1 ? 2u : 0u)
                        | (c0.z == my1 ? 4u : 0u) | (c0.w == my1 ? 8u : 0u);

            unsigned p0m = e0 & m0v, n0m = (~e0) & m0v;
            unsigned p1m = e1 & m1v, n1m = (~e1) & m1v;
            unsigned long long bp0 = __ballot(p0m != 0u);
            unsigned long long bn0 = __ballot(n0m != 0u);
            unsigned long long bp1 = __ballot(p1m != 0u);
            unsigned long long bn1 = __ballot(n1m != 0u);

            if (!fp0 && bp0) { fp0 = true; balP0 = bp0; baseP0 = kbase; msP0 = p0m; }
            if (!fn0 && bn0) { fn0 = true; balN0 = bn0; baseN0 = kbase; msN0 = n0m; }
            if (has1) {
                if (!fp1 && bp1) { fp1 = true; balP1 = bp1; baseP1 = kbase; msP1 = p1m; }
                if (!fn1 && bn1) { fn1 = true; balN1 = bn1; baseN1 = kbase; msN1 = n1m; }
            }

            kbase += 64;
            if ((fp0 && fn0 && fp1 && fn1) || kbase >= nq) break;
            c0 = c1; c1 = c2;
            mv0 = 0xFu; mv1 = 0xFu;
        }
    }

    // Resolve exact indices: shfl + ffs only (no memory on the chain).
    int p0 = 0, ng0 = 0, p1 = 0, ng1 = 0;
    if (balP0) { int ls = (int)__ffsll(balP0) - 1; unsigned m = __shfl(msP0, ls);
                 p0  = ((baseP0 + ls) << 2) + (__ffs(m) - 1); }
    if (balN0) { int ls = (int)__ffsll(balN0) - 1; unsigned m = __shfl(msN0, ls);
                 ng0 = ((baseN0 + ls) << 2) + (__ffs(m) - 1); }
    if (balP1) { int ls = (int)__ffsll(balP1) - 1; unsigned m = __shfl(msP1, ls);
                 p1  = ((baseP1 + ls) << 2) + (__ffs(m) - 1); }
    if (balN1) { int ls = (int)__ffsll(balN1) - 1; unsigned m = __shfl(msN1, ls);
                 ng1 = ((baseN1 + ls) << 2) + (__ffs(m) - 1); }

    float v0 = (balP0 && balN0) ? 1.0f : 0.0f;
    float v1 = (balP1 && balN1) ? 1.0f : 0.0f;

    if (lane < 2 && i0 + lane < N)
        valid_out[i0 + lane] = lane ? v1 : v0;

    // Combined gathers: lanes<32 -> neg row, lanes>=32 -> pos row (per anchor).
    size_t ND4 = (size_t)N * D4;
    int g0 = (lane < 32) ? ng0 : p0;
    f32x4 eg0 = emb[(size_t)g0 * D4 + d4];
    int g1 = (lane < 32) ? ng1 : p1;
    f32x4 eg1 = has1 ? emb[(size_t)g1 * D4 + d4] : f32x4{0, 0, 0, 0};

    int t = lane >> 5;
    f32x4 r0 = (lane < 32) ? ea0 : eg0;
    out[(size_t)t * ND4 + (size_t)i0 * D4 + d4] = r0 * v0;     // anchor0 | pos0
    if (lane < 32)
        out[2 * ND4 + (size_t)i0 * D4 + d4] = eg0 * v0;        // neg0

    if (has1) {
        f32x4 r1 = (lane < 32) ? ea1 : eg1;
        out[(size_t)t * ND4 + (size_t)i1 * D4 + d4] = r1 * v1; // anchor1 | pos1
        if (lane < 32)
            out[2 * ND4 + (size_t)i1 * D4 + d4] = eg1 * v1;    // neg1
    }
}

extern "C" void kernel_launch(void* const* d_in, const int* in_sizes, int n_in,
                              void* d_out, int out_size, void* d_ws, size_t ws_size,
                              hipStream_t stream) {
    const float* emb    = (const float*)d_in[0];
    const int*   labels = (const int*)d_in[1];   // harness passes integers as int32

    int N = in_sizes[1];             // 16384
    int D = in_sizes[0] / N;         // 128 (D4 = 32 hard-wired in kernel)

    float* out       = (float*)d_out;
    float* valid_out = out + (size_t)3 * N * D;  // tail of d_out: [N] valid mask

    int waves = (N + 1) / 2;                     // two anchors per wave
    int nblk  = (waves * 64 + BLOCK - 1) / BLOCK;
    triplet_fused_kernel<<<nblk, BLOCK, 0, stream>>>(
        labels, (const f32x4*)emb, (f32x4*)out, valid_out, N);
}

// Round 16
// 15.436 us; speedup vs baseline: 7.0154x; 1.2231x over previous
//
#include <hip/hip_runtime.h>

typedef float f32x4 __attribute__((ext_vector_type(4)));

#define BLOCK 256   // 4 waves per block, one anchor per wave

// Fused triplet miner: ONE WAVE per anchor, straight-line 2048-label warmup.
//  - 8 independent int4 loads (4 groups x 512 labels) issued upfront: all
//    complete under ~one L2 latency. Covers pos-gap <= 2048 (~87% of anchors)
//    with ZERO load-dependent stalls in the mining chain.
//  - per group: 8 compares -> 8-bit mask -> 2 ballots; match masks captured;
//    post-loop resolve is shfl+ffs only.
//  - rare tail (~13%): round-12's 2-deep prefetch loop from label 2048 on.
//  - anchor emb row loaded before mining; pos+neg rows one combined gather.
//  - normal (L2) stores for the 25 MB output stream.
__global__ void __launch_bounds__(BLOCK) triplet_fused_kernel(
    const int* __restrict__ labels,
    const f32x4* __restrict__ emb,    // [N][32]
    f32x4* __restrict__ out,          // [3][N][32]
    float* __restrict__ valid_out,    // [N]
    int N) {

    const int D4 = 32;
    int lane = threadIdx.x & 63;
    int i = blockIdx.x * (BLOCK >> 6) + (threadIdx.x >> 6);   // anchor (wave-uniform)
    if (i >= N) return;

    // Early independent loads: anchor embedding row + anchor label.
    int d4 = lane & 31;
    f32x4 ea = emb[(size_t)i * D4 + d4];
    int my = labels[i];

    const int4* lab4 = (const int4*)labels;
    int nq = N >> 2;                       // N % 4 == 0
    int kb = (i + 1) >> 2;                 // first chunk containing j > i

    // Lane-0 leading mask for group 0 (entries with j <= i in its first chunk).
    unsigned mv_lead = 0xFFu;
    if (lane == 0) {
        int nclr = i + 1 - (kb << 2);      // 0..3
        mv_lead = 0xFFu << nclr;
    }

    // Warmup: 4 groups x 512 labels = 2048, all 8 loads issued upfront.
    int c0 = kb + 2 * lane;
    int4 A0 = lab4[min(c0,       nq - 1)];
    int4 B0 = lab4[min(c0 + 1,   nq - 1)];
    int4 A1 = lab4[min(c0 + 128, nq - 1)];
    int4 B1 = lab4[min(c0 + 129, nq - 1)];
    int4 A2 = lab4[min(c0 + 256, nq - 1)];
    int4 B2 = lab4[min(c0 + 257, nq - 1)];
    int4 A3 = lab4[min(c0 + 384, nq - 1)];
    int4 B3 = lab4[min(c0 + 385, nq - 1)];

    bool fp = false, fn = false;
    unsigned long long balp = 0, baln = 0;
    int basep = 0, basen = 0;
    unsigned msp = 0, msn = 0;

    auto process = [&](int4 A, int4 B, int gbase, unsigned lead) {
        int kq0 = gbase + 2 * lane, kq1 = kq0 + 1;
        unsigned mv = lead;
        if (kq0 >= nq)      mv = 0;
        else if (kq1 >= nq) mv &= 0x0Fu;
        unsigned ms = (A.x == my ?   1u : 0u) | (A.y == my ?   2u : 0u)
                    | (A.z == my ?   4u : 0u) | (A.w == my ?   8u : 0u)
                    | (B.x == my ?  16u : 0u) | (B.y == my ?  32u : 0u)
                    | (B.z == my ?  64u : 0u) | (B.w == my ? 128u : 0u);
        unsigned mp = ms & mv, mn = (~ms) & mv;
        unsigned long long bp = __ballot(mp != 0u);
        unsigned long long bn = __ballot(mn != 0u);
        if (!fp && bp) { fp = true; balp = bp; basep = gbase; msp = mp; }
        if (!fn && bn) { fn = true; baln = bn; basen = gbase; msn = mn; }
    };

    process(A0, B0, kb, mv_lead);
    if (!(fp && fn)) process(A1, B1, kb + 128, 0xFFu);
    if (!(fp && fn)) process(A2, B2, kb + 256, 0xFFu);
    if (!(fp && fn)) process(A3, B3, kb + 384, 0xFFu);

    // Rare tail (~13%): 2-deep prefetch loop from chunk kb+512 (label 2048+).
    if (!(fp && fn) && kb + 512 < nq) {
        int kbase = kb + 512;
        int4 a0 = lab4[min(kbase + 2 * lane,       nq - 1)];
        int4 b0 = lab4[min(kbase + 2 * lane + 1,   nq - 1)];
        int4 a1 = lab4[min(kbase + 128 + 2 * lane,     nq - 1)];
        int4 b1 = lab4[min(kbase + 128 + 2 * lane + 1, nq - 1)];
        while (true) {
            int4 a2 = lab4[min(kbase + 256 + 2 * lane,     nq - 1)];
            int4 b2 = lab4[min(kbase + 256 + 2 * lane + 1, nq - 1)];

            process(a0, b0, kbase, 0xFFu);

            kbase += 128;
            if ((fp && fn) || kbase >= nq) break;
            a0 = a1; b0 = b1; a1 = a2; b1 = b2;
        }
    }

    // Resolve exact indices: shfl + ffs only (no memory on the chain).
    int p = 0, ng = 0;
    if (fp) { int ls = (int)__ffsll(balp) - 1; unsigned m = __shfl(msp, ls);
              p  = ((basep + 2 * ls) << 2) + (__ffs(m) - 1); }
    if (fn) { int ls = (int)__ffsll(baln) - 1; unsigned m = __shfl(msn, ls);
              ng = ((basen + 2 * ls) << 2) + (__ffs(m) - 1); }

    float v = (fp && fn) ? 1.0f : 0.0f;
    if (lane == 0) valid_out[i] = v;

    // Combined gather: lanes<32 -> neg row, lanes>=32 -> pos row (one instr).
    size_t ND4 = (size_t)N * D4;
    int gsrc = (lane < 32) ? ng : p;
    f32x4 eg = emb[(size_t)gsrc * D4 + d4];

    // Pass 1: lanes<32 store anchor row (t=0), lanes>=32 store pos row (t=1).
    int   t  = lane >> 5;
    f32x4 r0 = (lane < 32) ? ea : eg;
    out[(size_t)t * ND4 + (size_t)i * D4 + d4] = r0 * v;

    // Pass 2: lanes<32 store neg row (t=2).
    if (lane < 32)
        out[2 * ND4 + (size_t)i * D4 + d4] = eg * v;
}

extern "C" void kernel_launch(void* const* d_in, const int* in_sizes, int n_in,
                              void* d_out, int out_size, void* d_ws, size_t ws_size,
                              hipStream_t stream) {
    const float* emb    = (const float*)d_in[0];
    const int*   labels = (const int*)d_in[1];   // harness passes integers as int32

    int N = in_sizes[1];             // 16384
    int D = in_sizes[0] / N;         // 128 (D4 = 32 hard-wired in kernel)

    float* out       = (float*)d_out;
    float* valid_out = out + (size_t)3 * N * D;  // tail of d_out: [N] valid mask

    int nblk = (N * 64 + BLOCK - 1) / BLOCK;     // one wave per anchor
    triplet_fused_kernel<<<nblk, BLOCK, 0, stream>>>(
        labels, (const f32x4*)emb, (f32x4*)out, valid_out, N);
}